// Round 4
// baseline (39.936 us; speedup 1.0000x reference)
//
#include <hip/hip_runtime.h>
#include <math.h>

#define NPTS 4096
#define NBATCH 8

// 3-op sorted-triple insert via med3 (rank-k insert identity). Keeps t0<=t1<=t2.
#define INS3(t0, t1, t2, v)                                   \
    {                                                         \
        float n0 = fminf(t0, (v));                            \
        float n1 = __builtin_amdgcn_fmed3f(t0, t1, (v));      \
        float n2 = __builtin_amdgcn_fmed3f(t1, t2, (v));      \
        t0 = n0; t1 = n1; t2 = n2;                            \
    }

// Merge partner's sorted triple (7 min/max) via xor-butterfly step.
#define MERGE3(t0, t1, t2, m)                                 \
    {                                                         \
        float b0 = __shfl_xor(t0, m);                         \
        float b1 = __shfl_xor(t1, m);                         \
        float b2 = __shfl_xor(t2, m);                         \
        float X = fmaxf(t0, b0);                              \
        t0 = fminf(t0, b0);                                   \
        float Y = fminf(t1, b1);                              \
        float Z = fmaxf(X, Y);                                \
        t1 = fminf(X, Y);                                     \
        t2 = fminf(Z, fminf(t2, b2));                         \
    }

#define RFL(x) __uint_as_float(__builtin_amdgcn_readfirstlane(__float_as_uint(x)))

// Declare query j: coefs forced into SGPRs (wave-uniform), triple in VGPRs.
#define DECLQ(j)                                              \
    float4 Q##j = lp4[qb + j];                                \
    float qx##j = RFL(-2.0f * Q##j.x);                        \
    float qy##j = RFL(-2.0f * Q##j.y);                        \
    float qz##j = RFL(-2.0f * Q##j.z);                        \
    float sq##j = RFL(Q##j.w);                                \
    float t##j##0 = INFINITY, t##j##1 = INFINITY, t##j##2 = INFINITY;

#define STEP(j)                                                             \
    {                                                                       \
        float e = fmaf(qx##j, c.x, fmaf(qy##j, c.y, fmaf(qz##j, c.z, c.w)));\
        INS3(t##j##0, t##j##1, t##j##2, e);                                 \
    }

// self's e = -|p|^2 is the strict minimum on its lane -> shift triple there.
#define SELF(j)                                                             \
    if (lane == (((w << 3) + j) & 63)) {                                    \
        t##j##0 = t##j##1; t##j##1 = t##j##2; t##j##2 = INFINITY;           \
    }

#define MRG(j, m) MERGE3(t##j##0, t##j##1, t##j##2, m)

#define DENS(j)                                                             \
    float d##j = (sqrtf(fmaxf(t##j##0 + sq##j, 1e-12f)) +                   \
                  sqrtf(fmaxf(t##j##1 + sq##j, 1e-12f)) +                   \
                  sqrtf(fmaxf(t##j##2 + sq##j, 1e-12f))) * (1.0f / 3.0f);

// One fused kernel. Block = 1024 thr = 16 waves; block owns 128 queries of one
// batch; wave owns 8 queries (coefs in SGPR), lanes hold candidates (1
// ds_read_b128 serves 64 cand x 8 queries). Centroid reduced from staged LDS;
// coeff fold done per-block by threads<128 (L2-served). Epilogue = 128x128 tile.
__launch_bounds__(1024, 4)
__global__ void fused_kernel(const float* __restrict__ pts,
                             const float* __restrict__ W_rel, const float* __restrict__ b_rel,
                             const float* __restrict__ W_dist, const float* __restrict__ b_dist,
                             const float* __restrict__ W_dens, const float* __restrict__ b_dens,
                             const float* __restrict__ W_out, const float* __restrict__ b_out,
                             float* __restrict__ out) {
    __shared__ float4 lp4[NPTS];                 // 64 KB: (x,y,z,|p|^2)
    __shared__ float4 cpart[16];
    __shared__ float4 cent;
    __shared__ __align__(16) float Clds[6][128]; // folded coeffs
    __shared__ float dens[128];

    int b = blockIdx.x >> 5;
    int g = blockIdx.x & 31;
    int tid = threadIdx.x;
    int w = tid >> 6, lane = tid & 63;

    // ---- stage points + centroid partial sums ----
    {
        const float4* P4 = (const float4*)(pts + (size_t)b * NPTS * 3);
        float4 v0 = P4[3 * tid + 0];
        float4 v1 = P4[3 * tid + 1];
        float4 v2 = P4[3 * tid + 2];
        float x0 = v0.x, y0 = v0.y, z0 = v0.z;
        float x1 = v0.w, y1 = v1.x, z1 = v1.y;
        float x2 = v1.z, y2 = v1.w, z2 = v2.x;
        float x3 = v2.y, y3 = v2.z, z3 = v2.w;
        lp4[4 * tid + 0] = make_float4(x0, y0, z0, fmaf(x0, x0, fmaf(y0, y0, z0 * z0)));
        lp4[4 * tid + 1] = make_float4(x1, y1, z1, fmaf(x1, x1, fmaf(y1, y1, z1 * z1)));
        lp4[4 * tid + 2] = make_float4(x2, y2, z2, fmaf(x2, x2, fmaf(y2, y2, z2 * z2)));
        lp4[4 * tid + 3] = make_float4(x3, y3, z3, fmaf(x3, x3, fmaf(y3, y3, z3 * z3)));
        float sx = (x0 + x1) + (x2 + x3);
        float sy = (y0 + y1) + (y2 + y3);
        float sz = (z0 + z1) + (z2 + z3);
        #pragma unroll
        for (int m = 1; m < 64; m <<= 1) {
            sx += __shfl_xor(sx, m);
            sy += __shfl_xor(sy, m);
            sz += __shfl_xor(sz, m);
        }
        if (lane == 0) cpart[w] = make_float4(sx, sy, sz, 0.f);
    }
    __syncthreads();

    // ---- wave 0: finish centroid; threads<128: coeff fold ----
    if (w == 0 && lane < 16) {
        float4 p = cpart[lane];
        float cx = p.x, cy = p.y, cz = p.z;
        #pragma unroll
        for (int m = 1; m < 16; m <<= 1) {
            cx += __shfl_xor(cx, m);
            cy += __shfl_xor(cy, m);
            cz += __shfl_xor(cz, m);
        }
        if (lane == 0) {
            const float inv = 1.0f / (float)NPTS;
            cent = make_float4(cx * inv, cy * inv, cz * inv, 0.f);
        }
    }
    if (tid < 128) {
        int o = tid;
        float a0 = 0.f, a1 = 0.f, a2 = 0.f, vd = 0.f, vl = 0.f, be = b_out[o];
        for (int j = 0; j < 42; ++j) {
            float w0 = W_out[j * 128 + o];
            float w1 = W_out[(42 + j) * 128 + o];
            float w2 = W_out[(84 + j) * 128 + o];
            a0 = fmaf(W_rel[j],      w0, a0);
            a1 = fmaf(W_rel[42 + j], w0, a1);
            a2 = fmaf(W_rel[84 + j], w0, a2);
            vd = fmaf(W_dist[j],     w1, vd);
            vl = fmaf(W_dens[j],     w2, vl);
            be = fmaf(b_rel[j],  w0, be);
            be = fmaf(b_dist[j], w1, be);
            be = fmaf(b_dens[j], w2, be);
        }
        Clds[0][o] = a0; Clds[1][o] = a1; Clds[2][o] = a2;
        Clds[3][o] = vd; Clds[4][o] = vl; Clds[5][o] = be;
    }

    // ---- scan: 8 queries per wave, lanes hold candidates ----
    int qb = (g << 7) + (w << 3);
    DECLQ(0) DECLQ(1) DECLQ(2) DECLQ(3) DECLQ(4) DECLQ(5) DECLQ(6) DECLQ(7)

    #pragma unroll 4
    for (int tile = 0; tile < 64; ++tile) {
        float4 c = lp4[(tile << 6) + lane];
        STEP(0) STEP(1) STEP(2) STEP(3) STEP(4) STEP(5) STEP(6) STEP(7)
    }

    SELF(0) SELF(1) SELF(2) SELF(3) SELF(4) SELF(5) SELF(6) SELF(7)

    #pragma unroll
    for (int m = 1; m < 64; m <<= 1) {
        MRG(0, m) MRG(1, m) MRG(2, m) MRG(3, m)
        MRG(4, m) MRG(5, m) MRG(6, m) MRG(7, m)
    }

    DENS(0) DENS(1) DENS(2) DENS(3) DENS(4) DENS(5) DENS(6) DENS(7)
    if (lane == 0) {
        int db = w << 3;
        dens[db + 0] = d0; dens[db + 1] = d1; dens[db + 2] = d2; dens[db + 3] = d3;
        dens[db + 4] = d4; dens[db + 5] = d5; dens[db + 6] = d6; dens[db + 7] = d7;
    }
    __syncthreads();

    // ---- epilogue: 128 rows x 128 cols; thread -> (row, 16 cols) ----
    {
        int r = tid >> 3;
        int c16 = (tid & 7) << 4;
        float4 p = lp4[(g << 7) + r];
        float rx = p.x - cent.x, ry = p.y - cent.y, rz = p.z - cent.z;
        float cd = sqrtf(fmaf(rx, rx, fmaf(ry, ry, rz * rz)));
        float ld = dens[r];
        float* orow = out + ((size_t)(b * NPTS + (g << 7) + r)) * 128;
        #pragma unroll
        for (int h = 0; h < 4; ++h) {
            int o = c16 + 4 * h;
            float4 A0 = *(const float4*)&Clds[0][o];
            float4 A1 = *(const float4*)&Clds[1][o];
            float4 A2 = *(const float4*)&Clds[2][o];
            float4 VD = *(const float4*)&Clds[3][o];
            float4 VL = *(const float4*)&Clds[4][o];
            float4 BE = *(const float4*)&Clds[5][o];
            float4 rv;
            rv.x = fmaf(rx, A0.x, fmaf(ry, A1.x, fmaf(rz, A2.x, fmaf(cd, VD.x, fmaf(ld, VL.x, BE.x)))));
            rv.y = fmaf(rx, A0.y, fmaf(ry, A1.y, fmaf(rz, A2.y, fmaf(cd, VD.y, fmaf(ld, VL.y, BE.y)))));
            rv.z = fmaf(rx, A0.z, fmaf(ry, A1.z, fmaf(rz, A2.z, fmaf(cd, VD.z, fmaf(ld, VL.z, BE.z)))));
            rv.w = fmaf(rx, A0.w, fmaf(ry, A1.w, fmaf(rz, A2.w, fmaf(cd, VD.w, fmaf(ld, VL.w, BE.w)))));
            *(float4*)(orow + o) = rv;
        }
    }
}

extern "C" void kernel_launch(void* const* d_in, const int* in_sizes, int n_in,
                              void* d_out, int out_size, void* d_ws, size_t ws_size,
                              hipStream_t stream) {
    const float* pts    = (const float*)d_in[0];
    const float* W_rel  = (const float*)d_in[1];
    const float* b_rel  = (const float*)d_in[2];
    const float* W_dist = (const float*)d_in[3];
    const float* b_dist = (const float*)d_in[4];
    const float* W_dens = (const float*)d_in[5];
    const float* b_dens = (const float*)d_in[6];
    const float* W_out  = (const float*)d_in[7];
    const float* b_out  = (const float*)d_in[8];
    float* out = (float*)d_out;

    hipLaunchKernelGGL(fused_kernel, dim3(NBATCH * 32), dim3(1024), 0, stream,
                       pts, W_rel, b_rel, W_dist, b_dist, W_dens, b_dens, W_out, b_out, out);
}